// Round 1
// baseline (69064.197 us; speedup 1.0000x reference)
//
#include <hip/hip_runtime.h>

// LSTM: T=512, B=64, IN=512, H=1024, 4H=4096, LAYERS=4, OUT=1
// Strategy: bf16 MFMA (16x16x32) everywhere, fp32 accum, fp32 cell state in regs.
//   - gemm_gx: per-layer input GEMM G = X @ W_ih^T + bias (chunked 64 timesteps)
//   - lstm_recur: 64 steps per launch, 64 WGs, inter-WG monotonic atomic barrier.
//     WG w owns hidden units [16w,16w+16) -> rows {u,1024+u,2048+u,3072+u}.
//     16 waves = (gate g in 0..3, batch-block mb in 0..3), each one 16x16 MFMA tile.
//   - head: out[t] = sum_j sigmoid(h[t][63][j]) * fc_w[j] + fc_b

typedef unsigned short u16;
typedef short bf16x8 __attribute__((ext_vector_type(8)));   // 8 bf16 in 4 VGPRs (guide §3)
typedef float f32x4 __attribute__((ext_vector_type(4)));

__device__ __forceinline__ u16 f2bf(float f) {
  unsigned u = __float_as_uint(f);
  return (u16)((u + 0x7FFFu + ((u >> 16) & 1u)) >> 16);   // RNE
}
__device__ __forceinline__ float bf2f(u16 s) {
  return __uint_as_float(((unsigned)s) << 16);
}
__device__ __forceinline__ bf16x8 ld8(const u16* p) {
  uint4 v = *(const uint4*)p;
  return __builtin_bit_cast(bf16x8, v);
}
__device__ __forceinline__ float sigf(float x) {
  x = fminf(fmaxf(x, -30.f), 30.f);
  return 1.f / (1.f + __expf(-x));
}
__device__ __forceinline__ float tanhf_(float x) {
  x = fminf(fmaxf(x, -15.f), 15.f);
  float e = __expf(-2.f * x);
  return (1.f - e) / (1.f + e);
}

// ---------------- conversions ----------------
__global__ void cvt4(const float4* __restrict__ s, u16* __restrict__ d, int n4) {
  int i = blockIdx.x * blockDim.x + threadIdx.x;
  if (i < n4) {
    float4 v = s[i];
    u16* o = d + 4 * (size_t)i;
    o[0] = f2bf(v.x); o[1] = f2bf(v.y); o[2] = f2bf(v.z); o[3] = f2bf(v.w);
  }
}

__global__ void bias_add(const float* __restrict__ a, const float* __restrict__ b,
                         float* __restrict__ o) {
  int i = blockIdx.x * blockDim.x + threadIdx.x;   // 16384 total
  o[i] = a[i] + b[i];
}

// ---------------- input GEMM: G[m][n] = sum_k X[m][k] W[n][k] + bias[n] ----------------
// M = 4096 (64 timesteps * 64 batch) per chunk, N = 4096, K = Kd (512 or 1024).
// 128x128 tile / WG, 4 waves each 64x64 (4x4 accs of 16x16x32). LDS padded stride 40
// (bank-conflict-free-ish, keeps 16B alignment for ds_read_b128).
#define LDP 40

__global__ __launch_bounds__(256, 2) void gemm_gx(
    const u16* __restrict__ Xb, int Kd,
    const u16* __restrict__ Wb,
    const float* __restrict__ bias,
    u16* __restrict__ Gb) {
  __shared__ u16 As[128 * LDP];
  __shared__ u16 Bs[128 * LDP];
  const int tid = threadIdx.x;
  const int wave = tid >> 6, lane = tid & 63;
  const int rL = lane & 15, qL = lane >> 4;
  const int m0 = blockIdx.y * 128, n0 = blockIdx.x * 128;

  // staging: each thread stages 2 A-chunks + 2 B-chunks of 8 bf16
  const int srow = tid >> 2, scol = (tid & 3) * 8;
  const u16* gA0 = Xb + (size_t)(m0 + srow) * Kd + scol;
  const u16* gA1 = Xb + (size_t)(m0 + 64 + srow) * Kd + scol;
  const u16* gB0 = Wb + (size_t)(n0 + srow) * Kd + scol;
  const u16* gB1 = Wb + (size_t)(n0 + 64 + srow) * Kd + scol;
  const int sOff = srow * LDP + scol;
  const int sOff1 = sOff + 64 * LDP;

  f32x4 acc[4][4];
#pragma unroll
  for (int i = 0; i < 4; ++i)
#pragma unroll
    for (int j = 0; j < 4; ++j) acc[i][j] = {0.f, 0.f, 0.f, 0.f};

  uint4 ra0 = *(const uint4*)gA0, ra1 = *(const uint4*)gA1;
  uint4 rb0 = *(const uint4*)gB0, rb1 = *(const uint4*)gB1;

  const int m0w = 64 * (wave >> 1), n0w = 64 * (wave & 1);
  const int nk = Kd >> 5;
  for (int kt = 0; kt < nk; ++kt) {
    __syncthreads();                       // prior LDS reads done
    *(uint4*)&As[sOff]  = ra0; *(uint4*)&As[sOff1] = ra1;
    *(uint4*)&Bs[sOff]  = rb0; *(uint4*)&Bs[sOff1] = rb1;
    __syncthreads();                       // writes visible
    if (kt + 1 < nk) {                     // prefetch next K-tile under the MFMAs
      int ko = (kt + 1) << 5;
      ra0 = *(const uint4*)(gA0 + ko); ra1 = *(const uint4*)(gA1 + ko);
      rb0 = *(const uint4*)(gB0 + ko); rb1 = *(const uint4*)(gB1 + ko);
    }
    bf16x8 av[4], bv[4];
#pragma unroll
    for (int i = 0; i < 4; ++i) av[i] = ld8(&As[(m0w + 16 * i + rL) * LDP + qL * 8]);
#pragma unroll
    for (int j = 0; j < 4; ++j) bv[j] = ld8(&Bs[(n0w + 16 * j + rL) * LDP + qL * 8]);
#pragma unroll
    for (int i = 0; i < 4; ++i)
#pragma unroll
      for (int j = 0; j < 4; ++j)
        acc[i][j] = __builtin_amdgcn_mfma_f32_16x16x32_bf16(av[i], bv[j], acc[i][j], 0, 0, 0);
  }

  // epilogue: C/D layout col=lane&15 (n), row=qL*4+r (m)  [guide §3, m89-verified]
#pragma unroll
  for (int j = 0; j < 4; ++j) {
    float bv = bias[n0 + n0w + 16 * j + rL];
#pragma unroll
    for (int i = 0; i < 4; ++i)
#pragma unroll
      for (int r = 0; r < 4; ++r) {
        int m = m0 + m0w + 16 * i + qL * 4 + r;
        int n = n0 + n0w + 16 * j + rL;
        Gb[(size_t)m * 4096 + n] = f2bf(acc[i][j][r] + bv);
      }
  }
}

// ---------------- recurrence: 64 timesteps per launch ----------------
__global__ __launch_bounds__(1024) void lstm_recur(
    const u16* __restrict__ G,     // [64*64][4096] bf16 (bias included)
    const u16* __restrict__ Whh,   // [4096][1024] bf16
    u16* __restrict__ Hout,        // [T*B][1024] bf16
    u16* __restrict__ HST,         // [2][64][1024] bf16 (double-buffered h)
    float* __restrict__ CST,       // [64][1024] fp32 (cell, cross-chunk only)
    unsigned* __restrict__ bar,    // monotonic barrier counter
    int t0, int gb0) {
  __shared__ float P[4][64][16];
  const int tid = threadIdx.x;
  const int lane = tid & 63, wv = tid >> 6;
  const int g = wv & 3, mb = wv >> 2;
  const int w = blockIdx.x;            // units [16w, 16w+16)
  const int rL = lane & 15, qL = lane >> 4;

  // B-operand: W row (1024g + 16w + rL), 8 consecutive k at qL*8
  const u16* Wp = Whh + (size_t)(1024 * g + 16 * w + rL) * 1024 + qL * 8;
  const int abatch = 16 * mb + rL;     // A-operand: h row = batch
  const int aoff = qL * 8;

  const int ub = tid & 15, bb = tid >> 4;   // gating: thread owns (batch bb, unit ub)
  const int col = 16 * w + ub;

  float creg = (t0 == 0) ? 0.f : CST[bb * 1024 + col];

  for (int t = t0; t < t0 + 64; ++t) {
    f32x4 acc = {0.f, 0.f, 0.f, 0.f};
    if (t > 0) {                       // h == 0 at t=0: skip GEMM
      const u16* Ap = HST + (size_t)(t & 1) * 65536 + (size_t)abatch * 1024 + aoff;
#pragma unroll 8
      for (int k = 0; k < 1024; k += 32)
        acc = __builtin_amdgcn_mfma_f32_16x16x32_bf16(ld8(Ap + k), ld8(Wp + k), acc, 0, 0, 0);
    }
#pragma unroll
    for (int r = 0; r < 4; ++r) P[g][16 * mb + qL * 4 + r][rL] = acc[r];
    __syncthreads();
    {
      const u16* Gr = G + ((size_t)(t - t0) * 64 + bb) * 4096 + col;
      float pi = P[0][bb][ub] + bf2f(Gr[0]);
      float pf = P[1][bb][ub] + bf2f(Gr[1024]);
      float pg = P[2][bb][ub] + bf2f(Gr[2048]);
      float po = P[3][bb][ub] + bf2f(Gr[3072]);
      float iv = sigf(pi), fv = sigf(pf), gv = tanhf_(pg), ov = sigf(po);
      creg = fv * creg + iv * gv;
      float hv = ov * tanhf_(creg);
      u16 hb = f2bf(hv);
      HST[(size_t)((t + 1) & 1) * 65536 + bb * 1024 + col] = hb;
      Hout[((size_t)t * 64 + bb) * 1024 + col] = hb;
    }
    __syncthreads();   // all waves' global h-stores drained (vmcnt(0) before s_barrier)
    if (tid == 0) {
      __hip_atomic_fetch_add(bar, 1u, __ATOMIC_RELEASE, __HIP_MEMORY_SCOPE_AGENT);
      unsigned tgt = 64u * (unsigned)(gb0 + (t - t0) + 1);
      while (__hip_atomic_load(bar, __ATOMIC_ACQUIRE, __HIP_MEMORY_SCOPE_AGENT) < tgt)
        __builtin_amdgcn_s_sleep(1);
    }
    __syncthreads();
  }
  CST[bb * 1024 + col] = creg;
}

// ---------------- head ----------------
__global__ void lstm_head(const u16* __restrict__ Hl, const float* __restrict__ fcw,
                          const float* __restrict__ fcb, float* __restrict__ out) {
  int t = blockIdx.x, tid = threadIdx.x;
  const u16* hrow = Hl + ((size_t)t * 64 + 63) * 1024;   // batch index 63
  float s = 0.f;
  for (int j = tid; j < 1024; j += 256)
    s += sigf(bf2f(hrow[j])) * fcw[j];
  for (int o = 32; o; o >>= 1) s += __shfl_down(s, o, 64);
  __shared__ float red[4];
  if ((tid & 63) == 0) red[tid >> 6] = s;
  __syncthreads();
  if (tid == 0) out[t] = red[0] + red[1] + red[2] + red[3] + fcb[0];
}

// ---------------- launch ----------------
extern "C" void kernel_launch(void* const* d_in, const int* in_sizes, int n_in,
                              void* d_out, int out_size, void* d_ws, size_t ws_size,
                              hipStream_t stream) {
  const float* x    = (const float*)d_in[0];
  const float* wih0 = (const float*)d_in[1];
  const float* wihr = (const float*)d_in[2];
  const float* whh  = (const float*)d_in[3];
  const float* bih  = (const float*)d_in[4];
  const float* bhh  = (const float*)d_in[5];
  const float* fcw  = (const float*)d_in[6];
  const float* fcb  = (const float*)d_in[7];
  float* out = (float*)d_out;

  char* ws = (char*)d_ws;
  size_t off = 0;
  auto alc = [&](size_t b) { void* p = ws + off; off = (off + b + 255) & ~(size_t)255; return p; };
  u16* WIH   = (u16*)alc(4ull * 4096 * 1024 * 2);   // layer l at elem l*4194304 (l0: K=512)
  u16* WHH   = (u16*)alc(4ull * 4096 * 1024 * 2);
  float* BIAS = (float*)alc(4 * 4096 * 4);
  u16* XBUF  = (u16*)alc(32768ull * 1024 * 2);
  u16* HBUF  = (u16*)alc(32768ull * 1024 * 2);
  u16* GBUF  = (u16*)alc(64ull * 64 * 4096 * 2);    // one 64-step chunk of preactivations
  u16* HST   = (u16*)alc(2 * 64 * 1024 * 2);
  float* CST = (float*)alc(64 * 1024 * 4);
  unsigned* BAR = (unsigned*)alc(256);
  (void)ws_size; (void)in_sizes; (void)n_in; (void)out_size;

  hipMemsetAsync(BAR, 0, 256, stream);
  cvt4<<<dim3(4194304 / 256), 256, 0, stream>>>((const float4*)x,    XBUF, 4194304);
  cvt4<<<dim3(524288 / 256),  256, 0, stream>>>((const float4*)wih0, WIH, 524288);
  cvt4<<<dim3(3145728 / 256), 256, 0, stream>>>((const float4*)wihr, WIH + 4194304, 3145728);
  cvt4<<<dim3(4194304 / 256), 256, 0, stream>>>((const float4*)whh,  WHH, 4194304);
  bias_add<<<dim3(64), 256, 0, stream>>>(bih, bhh, BIAS);

  for (int l = 0; l < 4; ++l) {
    const u16* Xin = (l & 1) ? HBUF : XBUF;
    u16* Ho        = (l & 1) ? XBUF : HBUF;
    const int Kd = (l == 0) ? 512 : 1024;
    const u16* Wih   = WIH + (size_t)l * 4194304;
    const u16* Whh_l = WHH + (size_t)l * 4194304;
    for (int t0 = 0; t0 < 512; t0 += 64) {
      gemm_gx<<<dim3(32, 32), 256, 0, stream>>>(Xin + (size_t)t0 * 64 * Kd, Kd, Wih,
                                                BIAS + l * 4096, GBUF);
      lstm_recur<<<dim3(64), 1024, 0, stream>>>(GBUF, Whh_l, Ho, HST, CST, BAR,
                                                t0, l * 512 + t0);
    }
  }
  lstm_head<<<dim3(512), 256, 0, stream>>>(XBUF, fcw, fcb, out);
}

// Round 2
// 59409.216 us; speedup vs baseline: 1.1625x; 1.1625x over previous
//
#include <hip/hip_runtime.h>

// LSTM: T=512, B=64, IN=512, H=1024, 4H=4096, LAYERS=4, OUT=1
// R2: recurrence rebuilt — W_hh register-stationary (32x32x16 MFMA, k-split 4),
// h exchanged via 64-slot ring with system-scope write-through stores and plain
// cached reads (ring slot never reused within a dispatch -> always L2-cold ->
// fresh from LLC). No acquire fences / L2 invalidates anywhere in the loop.

typedef unsigned short u16;
typedef short bf16x8 __attribute__((ext_vector_type(8)));
typedef float f32x4 __attribute__((ext_vector_type(4)));
typedef float f32x16 __attribute__((ext_vector_type(16)));

__device__ __forceinline__ u16 f2bf(float f) {
  unsigned u = __float_as_uint(f);
  return (u16)((u + 0x7FFFu + ((u >> 16) & 1u)) >> 16);   // RNE
}
__device__ __forceinline__ float bf2f(u16 s) {
  return __uint_as_float(((unsigned)s) << 16);
}
__device__ __forceinline__ bf16x8 ld8(const u16* p) {
  uint4 v = *(const uint4*)p;
  return __builtin_bit_cast(bf16x8, v);
}
__device__ __forceinline__ float sigf(float x) {
  x = fminf(fmaxf(x, -30.f), 30.f);
  return 1.f / (1.f + __expf(-x));
}
__device__ __forceinline__ float tanhf_(float x) {
  x = fminf(fmaxf(x, -15.f), 15.f);
  float e = __expf(-2.f * x);
  return (1.f - e) / (1.f + e);
}

// ---------------- conversions ----------------
__global__ void cvt4(const float4* __restrict__ s, u16* __restrict__ d, int n4) {
  int i = blockIdx.x * blockDim.x + threadIdx.x;
  if (i < n4) {
    float4 v = s[i];
    u16* o = d + 4 * (size_t)i;
    o[0] = f2bf(v.x); o[1] = f2bf(v.y); o[2] = f2bf(v.z); o[3] = f2bf(v.w);
  }
}

__global__ void bias_add(const float* __restrict__ a, const float* __restrict__ b,
                         float* __restrict__ o) {
  int i = blockIdx.x * blockDim.x + threadIdx.x;   // 16384 total
  o[i] = a[i] + b[i];
}

// ---------------- input GEMM (unchanged from R1, passed) ----------------
#define LDP 40

__global__ __launch_bounds__(256, 2) void gemm_gx(
    const u16* __restrict__ Xb, int Kd,
    const u16* __restrict__ Wb,
    const float* __restrict__ bias,
    u16* __restrict__ Gb) {
  __shared__ u16 As[128 * LDP];
  __shared__ u16 Bs[128 * LDP];
  const int tid = threadIdx.x;
  const int wave = tid >> 6, lane = tid & 63;
  const int rL = lane & 15, qL = lane >> 4;
  const int m0 = blockIdx.y * 128, n0 = blockIdx.x * 128;

  const int srow = tid >> 2, scol = (tid & 3) * 8;
  const u16* gA0 = Xb + (size_t)(m0 + srow) * Kd + scol;
  const u16* gA1 = Xb + (size_t)(m0 + 64 + srow) * Kd + scol;
  const u16* gB0 = Wb + (size_t)(n0 + srow) * Kd + scol;
  const u16* gB1 = Wb + (size_t)(n0 + 64 + srow) * Kd + scol;
  const int sOff = srow * LDP + scol;
  const int sOff1 = sOff + 64 * LDP;

  f32x4 acc[4][4];
#pragma unroll
  for (int i = 0; i < 4; ++i)
#pragma unroll
    for (int j = 0; j < 4; ++j) acc[i][j] = {0.f, 0.f, 0.f, 0.f};

  uint4 ra0 = *(const uint4*)gA0, ra1 = *(const uint4*)gA1;
  uint4 rb0 = *(const uint4*)gB0, rb1 = *(const uint4*)gB1;

  const int m0w = 64 * (wave >> 1), n0w = 64 * (wave & 1);
  const int nk = Kd >> 5;
  for (int kt = 0; kt < nk; ++kt) {
    __syncthreads();
    *(uint4*)&As[sOff]  = ra0; *(uint4*)&As[sOff1] = ra1;
    *(uint4*)&Bs[sOff]  = rb0; *(uint4*)&Bs[sOff1] = rb1;
    __syncthreads();
    if (kt + 1 < nk) {
      int ko = (kt + 1) << 5;
      ra0 = *(const uint4*)(gA0 + ko); ra1 = *(const uint4*)(gA1 + ko);
      rb0 = *(const uint4*)(gB0 + ko); rb1 = *(const uint4*)(gB1 + ko);
    }
    bf16x8 av[4], bv[4];
#pragma unroll
    for (int i = 0; i < 4; ++i) av[i] = ld8(&As[(m0w + 16 * i + rL) * LDP + qL * 8]);
#pragma unroll
    for (int j = 0; j < 4; ++j) bv[j] = ld8(&Bs[(n0w + 16 * j + rL) * LDP + qL * 8]);
#pragma unroll
    for (int i = 0; i < 4; ++i)
#pragma unroll
      for (int j = 0; j < 4; ++j)
        acc[i][j] = __builtin_amdgcn_mfma_f32_16x16x32_bf16(av[i], bv[j], acc[i][j], 0, 0, 0);
  }

#pragma unroll
  for (int j = 0; j < 4; ++j) {
    float bv = bias[n0 + n0w + 16 * j + rL];
#pragma unroll
    for (int i = 0; i < 4; ++i)
#pragma unroll
      for (int r = 0; r < 4; ++r) {
        int m = m0 + m0w + 16 * i + qL * 4 + r;
        int n = n0 + n0w + 16 * j + rL;
        Gb[(size_t)m * 4096 + n] = f2bf(acc[i][j][r] + bv);
      }
  }
}

// ---------------- recurrence v2: 64 steps / launch, 64 WGs ----------------
// WG w owns units [16w,16w+16) -> 64 gate-rows (local row lr: g=lr>>4, u=lr&15).
// 16 waves = (ks in 0..3, mh in 0..1, nh in 0..1): 32x32 output tile
// (batch mh*32.., local rows nh*32..) over K-slice [256ks, 256ks+256).
// W slice held in 64 VGPRs (loaded once). h(t) stored k-major-8 [kc][b][8]
// into ring slot (gt&63) via system-scope dword stores; next step reads the
// slot with plain dwordx4 (cold in L2 -> served fresh from LLC).
__global__ __launch_bounds__(1024, 4) void lstm_recur(
    const u16* __restrict__ G,      // [64*64][4096] bf16, bias included
    const u16* __restrict__ Whh,    // [4096][1024] bf16
    u16* __restrict__ Hout,         // [T*B][1024] bf16 (plain)
    u16* __restrict__ HRING,        // [64][128][64][8] u16 ring (8 MB)
    float* __restrict__ CST,        // [64][1024] fp32 cell state
    unsigned* __restrict__ bar,     // monotonic barrier counter
    int t0, int gb0) {
  __shared__ float R[64 * 64];      // [b][lr] fp32 gate preacts (16 KB)
  const int tid = threadIdx.x;
  const int lane = tid & 63, wv = tid >> 6;
  const int ks = wv & 3, mh = (wv >> 2) & 1, nh = wv >> 3;
  const int w = blockIdx.x;
  const int l31 = lane & 31, lhi = lane >> 5;

  // ---- W preload: 16 frags = 64 VGPRs, persistent ----
  bf16x8 wf[16];
  {
    const int lr = nh * 32 + l31;
    const int grow = (lr >> 4) * 1024 + 16 * w + (lr & 15);
    const u16* wp = Whh + (size_t)grow * 1024 + ks * 256 + lhi * 8;
#pragma unroll
    for (int kk = 0; kk < 16; ++kk) wf[kk] = ld8(wp + kk * 16);
  }

  const int bb = tid >> 4, ub = tid & 15;      // gating: thread owns (batch bb, unit ub)
  const int col = 16 * w + ub;
  float creg = (t0 == 0) ? 0.f : CST[bb * 1024 + col];

  // A-frag element offset inside a ring slot (add kk*1024 per k-iter):
  // k = ks*256 + kk*16 + lhi*8 + j  ->  kc = ks*32 + 2kk + lhi; b = mh*32 + l31
  const int afrag_elem = ((ks * 32 + lhi) * 64 + mh * 32 + l31) * 8;
  const int lrD = nh * 32 + l31;               // C/D column -> local gate-row

  for (int tl = 0; tl < 64; ++tl) {
    const int lt = t0 + tl;          // layer-local step (0 -> h_prev = 0)
    const int gt = gb0 + tl;         // global step (ring slot & barrier index)

    // zero R (all 1024 threads, 4 floats each)
    *(f32x4*)&R[tid * 4] = f32x4{0.f, 0.f, 0.f, 0.f};
    // G prefetch (independent of h -> issues early, hides L2 latency)
    const u16* Gr = G + ((size_t)tl * 64 + bb) * 4096 + col;
    float g0 = bf2f(Gr[0]), g1 = bf2f(Gr[1024]), g2 = bf2f(Gr[2048]), g3 = bf2f(Gr[3072]);

    f32x16 acc = {};
    const bool doGemm = (lt > 0);
    if (doGemm) {
      const u16* Ab = HRING + (size_t)((gt - 1) & 63) * 65536 + afrag_elem;
      uint4 af[4];
#pragma unroll
      for (int p = 0; p < 4; ++p) af[p] = *(const uint4*)(Ab + p * 1024);
#pragma unroll
      for (int kk = 0; kk < 16; ++kk) {
        uint4 cur = af[kk & 3];
        if (kk + 4 < 16) af[kk & 3] = *(const uint4*)(Ab + (size_t)(kk + 4) * 1024);
        acc = __builtin_amdgcn_mfma_f32_32x32x16_bf16(
            __builtin_bit_cast(bf16x8, cur), wf[kk], acc, 0, 0, 0);
      }
    }
    __syncthreads();                 // R zeros visible
    if (doGemm) {
#pragma unroll
      for (int r = 0; r < 16; ++r) {
        int m = (r & 3) + 8 * (r >> 2) + 4 * lhi;    // 32x32 C/D row map (m101)
        atomicAdd(&R[(mh * 32 + m) * 64 + lrD], acc[r]);
      }
    }
    __syncthreads();                 // k-partial reduction done
    {
      float pi = R[bb * 64 + ub] + g0;
      float pf = R[bb * 64 + 16 + ub] + g1;
      float pg = R[bb * 64 + 32 + ub] + g2;
      float po = R[bb * 64 + 48 + ub] + g3;
      float iv = sigf(pi), fv = sigf(pf), gv = tanhf_(pg), ov = sigf(po);
      creg = fv * creg + iv * gv;
      float hv = ov * tanhf_(creg);
      u16 hb = f2bf(hv);
      // pack (u, u+1) into a dword; even-u lanes store
      unsigned hi = (unsigned)(u16)__shfl_down((int)(unsigned)hb, 1, 64);
      unsigned packed = (unsigned)hb | (hi << 16);
      if ((ub & 1) == 0) {
        // ring slot, k-major-8: elem = (col>>3)*512 + bb*8 + (col&7)
        size_t elem = ((size_t)(col >> 3) * 64 + bb) * 8 + (col & 7);
        unsigned* p = (unsigned*)(HRING + (size_t)(gt & 63) * 65536 + elem);
        __hip_atomic_store(p, packed, __ATOMIC_RELAXED, __HIP_MEMORY_SCOPE_SYSTEM);
        // Hout row-major [t][b][1024] (plain cached; flushed at kernel end)
        *(unsigned*)(Hout + ((size_t)lt * 64 + bb) * 1024 + col) = packed;
      }
    }
    __syncthreads();                 // per-wave vmcnt(0) drain before arrival
    if (tid == 0) {
      __hip_atomic_fetch_add(bar, 1u, __ATOMIC_RELEASE, __HIP_MEMORY_SCOPE_SYSTEM);
      unsigned tgt = 64u * (unsigned)(gt + 1);
      while (__hip_atomic_load(bar, __ATOMIC_RELAXED, __HIP_MEMORY_SCOPE_SYSTEM) < tgt)
        __builtin_amdgcn_s_sleep(2);
    }
    __syncthreads();
  }
  CST[bb * 1024 + col] = creg;
}

// ---------------- head ----------------
__global__ void lstm_head(const u16* __restrict__ Hl, const float* __restrict__ fcw,
                          const float* __restrict__ fcb, float* __restrict__ out) {
  int t = blockIdx.x, tid = threadIdx.x;
  const u16* hrow = Hl + ((size_t)t * 64 + 63) * 1024;   // batch index 63
  float s = 0.f;
  for (int j = tid; j < 1024; j += 256)
    s += sigf(bf2f(hrow[j])) * fcw[j];
  for (int o = 32; o; o >>= 1) s += __shfl_down(s, o, 64);
  __shared__ float red[4];
  if ((tid & 63) == 0) red[tid >> 6] = s;
  __syncthreads();
  if (tid == 0) out[t] = red[0] + red[1] + red[2] + red[3] + fcb[0];
}

// ---------------- launch ----------------
extern "C" void kernel_launch(void* const* d_in, const int* in_sizes, int n_in,
                              void* d_out, int out_size, void* d_ws, size_t ws_size,
                              hipStream_t stream) {
  const float* x    = (const float*)d_in[0];
  const float* wih0 = (const float*)d_in[1];
  const float* wihr = (const float*)d_in[2];
  const float* whh  = (const float*)d_in[3];
  const float* bih  = (const float*)d_in[4];
  const float* bhh  = (const float*)d_in[5];
  const float* fcw  = (const float*)d_in[6];
  const float* fcb  = (const float*)d_in[7];
  float* out = (float*)d_out;

  char* ws = (char*)d_ws;
  size_t off = 0;
  auto alc = [&](size_t b) { void* p = ws + off; off = (off + b + 255) & ~(size_t)255; return p; };
  u16* WIH   = (u16*)alc(4ull * 4096 * 1024 * 2);
  u16* WHH   = (u16*)alc(4ull * 4096 * 1024 * 2);
  float* BIAS = (float*)alc(4 * 4096 * 4);
  u16* XBUF  = (u16*)alc(32768ull * 1024 * 2);
  u16* HBUF  = (u16*)alc(32768ull * 1024 * 2);
  u16* GBUF  = (u16*)alc(64ull * 64 * 4096 * 2);
  u16* HRING = (u16*)alc(64ull * 65536 * 2);    // 8 MB h ring
  float* CST = (float*)alc(64 * 1024 * 4);
  unsigned* BAR = (unsigned*)alc(256);
  (void)ws_size; (void)in_sizes; (void)n_in; (void)out_size;

  hipMemsetAsync(BAR, 0, 256, stream);
  cvt4<<<dim3(4194304 / 256), 256, 0, stream>>>((const float4*)x,    XBUF, 4194304);
  cvt4<<<dim3(524288 / 256),  256, 0, stream>>>((const float4*)wih0, WIH, 524288);
  cvt4<<<dim3(3145728 / 256), 256, 0, stream>>>((const float4*)wihr, WIH + 4194304, 3145728);
  cvt4<<<dim3(4194304 / 256), 256, 0, stream>>>((const float4*)whh,  WHH, 4194304);
  bias_add<<<dim3(64), 256, 0, stream>>>(bih, bhh, BIAS);

  for (int l = 0; l < 4; ++l) {
    const u16* Xin = (l & 1) ? HBUF : XBUF;
    u16* Ho        = (l & 1) ? XBUF : HBUF;
    const int Kd = (l == 0) ? 512 : 1024;
    const u16* Wih   = WIH + (size_t)l * 4194304;
    const u16* Whh_l = WHH + (size_t)l * 4194304;
    for (int t0 = 0; t0 < 512; t0 += 64) {
      gemm_gx<<<dim3(32, 32), 256, 0, stream>>>(Xin + (size_t)t0 * 64 * Kd, Kd, Wih,
                                                BIAS + l * 4096, GBUF);
      lstm_recur<<<dim3(64), 1024, 0, stream>>>(GBUF, Whh_l, Ho, HRING, CST, BAR,
                                                t0, l * 512 + t0);
    }
  }
  lstm_head<<<dim3(512), 256, 0, stream>>>(XBUF, fcw, fcb, out);
}

// Round 3
// 54963.776 us; speedup vs baseline: 1.2565x; 1.0809x over previous
//
#include <hip/hip_runtime.h>

// LSTM: T=512, B=64, IN=512, H=1024, 4H=4096, LAYERS=4, OUT=1
// R3: distributed flag barrier — each WG has its own 128B-spaced flag line;
// arrival = one relaxed system-scope store; detection = wave 0 reads all 64
// flags in parallel (one per lane) + ballot. No atomics / release fences /
// buffer_wbl2 in the step loop (R2's single-counter RMW barrier was ~25 us/step).

typedef unsigned short u16;
typedef short bf16x8 __attribute__((ext_vector_type(8)));
typedef float f32x4 __attribute__((ext_vector_type(4)));
typedef float f32x16 __attribute__((ext_vector_type(16)));

__device__ __forceinline__ u16 f2bf(float f) {
  unsigned u = __float_as_uint(f);
  return (u16)((u + 0x7FFFu + ((u >> 16) & 1u)) >> 16);   // RNE
}
__device__ __forceinline__ float bf2f(u16 s) {
  return __uint_as_float(((unsigned)s) << 16);
}
__device__ __forceinline__ bf16x8 ld8(const u16* p) {
  uint4 v = *(const uint4*)p;
  return __builtin_bit_cast(bf16x8, v);
}
__device__ __forceinline__ float sigf(float x) {
  x = fminf(fmaxf(x, -30.f), 30.f);
  return 1.f / (1.f + __expf(-x));
}
__device__ __forceinline__ float tanhf_(float x) {
  x = fminf(fmaxf(x, -15.f), 15.f);
  float e = __expf(-2.f * x);
  return (1.f - e) / (1.f + e);
}

// ---------------- conversions ----------------
__global__ void cvt4(const float4* __restrict__ s, u16* __restrict__ d, int n4) {
  int i = blockIdx.x * blockDim.x + threadIdx.x;
  if (i < n4) {
    float4 v = s[i];
    u16* o = d + 4 * (size_t)i;
    o[0] = f2bf(v.x); o[1] = f2bf(v.y); o[2] = f2bf(v.z); o[3] = f2bf(v.w);
  }
}

__global__ void bias_add(const float* __restrict__ a, const float* __restrict__ b,
                         float* __restrict__ o) {
  int i = blockIdx.x * blockDim.x + threadIdx.x;   // 16384 total
  o[i] = a[i] + b[i];
}

// ---------------- input GEMM (unchanged, passing) ----------------
#define LDP 40

__global__ __launch_bounds__(256, 2) void gemm_gx(
    const u16* __restrict__ Xb, int Kd,
    const u16* __restrict__ Wb,
    const float* __restrict__ bias,
    u16* __restrict__ Gb) {
  __shared__ u16 As[128 * LDP];
  __shared__ u16 Bs[128 * LDP];
  const int tid = threadIdx.x;
  const int wave = tid >> 6, lane = tid & 63;
  const int rL = lane & 15, qL = lane >> 4;
  const int m0 = blockIdx.y * 128, n0 = blockIdx.x * 128;

  const int srow = tid >> 2, scol = (tid & 3) * 8;
  const u16* gA0 = Xb + (size_t)(m0 + srow) * Kd + scol;
  const u16* gA1 = Xb + (size_t)(m0 + 64 + srow) * Kd + scol;
  const u16* gB0 = Wb + (size_t)(n0 + srow) * Kd + scol;
  const u16* gB1 = Wb + (size_t)(n0 + 64 + srow) * Kd + scol;
  const int sOff = srow * LDP + scol;
  const int sOff1 = sOff + 64 * LDP;

  f32x4 acc[4][4];
#pragma unroll
  for (int i = 0; i < 4; ++i)
#pragma unroll
    for (int j = 0; j < 4; ++j) acc[i][j] = {0.f, 0.f, 0.f, 0.f};

  uint4 ra0 = *(const uint4*)gA0, ra1 = *(const uint4*)gA1;
  uint4 rb0 = *(const uint4*)gB0, rb1 = *(const uint4*)gB1;

  const int m0w = 64 * (wave >> 1), n0w = 64 * (wave & 1);
  const int nk = Kd >> 5;
  for (int kt = 0; kt < nk; ++kt) {
    __syncthreads();
    *(uint4*)&As[sOff]  = ra0; *(uint4*)&As[sOff1] = ra1;
    *(uint4*)&Bs[sOff]  = rb0; *(uint4*)&Bs[sOff1] = rb1;
    __syncthreads();
    if (kt + 1 < nk) {
      int ko = (kt + 1) << 5;
      ra0 = *(const uint4*)(gA0 + ko); ra1 = *(const uint4*)(gA1 + ko);
      rb0 = *(const uint4*)(gB0 + ko); rb1 = *(const uint4*)(gB1 + ko);
    }
    bf16x8 av[4], bv[4];
#pragma unroll
    for (int i = 0; i < 4; ++i) av[i] = ld8(&As[(m0w + 16 * i + rL) * LDP + qL * 8]);
#pragma unroll
    for (int j = 0; j < 4; ++j) bv[j] = ld8(&Bs[(n0w + 16 * j + rL) * LDP + qL * 8]);
#pragma unroll
    for (int i = 0; i < 4; ++i)
#pragma unroll
      for (int j = 0; j < 4; ++j)
        acc[i][j] = __builtin_amdgcn_mfma_f32_16x16x32_bf16(av[i], bv[j], acc[i][j], 0, 0, 0);
  }

#pragma unroll
  for (int j = 0; j < 4; ++j) {
    float bv = bias[n0 + n0w + 16 * j + rL];
#pragma unroll
    for (int i = 0; i < 4; ++i)
#pragma unroll
      for (int r = 0; r < 4; ++r) {
        int m = m0 + m0w + 16 * i + qL * 4 + r;
        int n = n0 + n0w + 16 * j + rL;
        Gb[(size_t)m * 4096 + n] = f2bf(acc[i][j][r] + bv);
      }
  }
}

// ---------------- recurrence v3: 64 steps / launch, 64 WGs ----------------
// WG w owns units [16w,16w+16) -> 64 gate-rows. 16 waves = (ks,mh,nh):
// 32x32 tile over K-slice 256ks..+256, W slice register-stationary (64 VGPRs).
// h ring: [64 slots][128][64][8] u16, system-scope write-through stores,
// plain cached reads (slot always L2-cold by the time it's reused).
// Barrier: FLAG[w*32] = steps completed (own 128B line); wave0 polls all 64
// flags one-per-lane with relaxed system loads + ballot.
__global__ __launch_bounds__(1024, 4) void lstm_recur(
    const u16* __restrict__ G,      // [64*64][4096] bf16, bias included
    const u16* __restrict__ Whh,    // [4096][1024] bf16
    u16* __restrict__ Hout,         // [T*B][1024] bf16 (plain)
    u16* __restrict__ HRING,        // [64][128][64][8] u16 ring (8 MB)
    float* __restrict__ CST,        // [64][1024] fp32 cell state
    unsigned* __restrict__ FLAG,    // [64][32] monotonic per-WG step flags
    int t0, int gb0) {
  __shared__ float R[64 * 64];      // [b][lr] fp32 gate preacts (16 KB)
  const int tid = threadIdx.x;
  const int lane = tid & 63, wv = tid >> 6;
  const int ks = wv & 3, mh = (wv >> 2) & 1, nh = wv >> 3;
  const int w = blockIdx.x;
  const int l31 = lane & 31, lhi = lane >> 5;

  // ---- W preload: 16 frags = 64 VGPRs, persistent ----
  bf16x8 wf[16];
  {
    const int lr = nh * 32 + l31;
    const int grow = (lr >> 4) * 1024 + 16 * w + (lr & 15);
    const u16* wp = Whh + (size_t)grow * 1024 + ks * 256 + lhi * 8;
#pragma unroll
    for (int kk = 0; kk < 16; ++kk) wf[kk] = ld8(wp + kk * 16);
  }

  const int bb = tid >> 4, ub = tid & 15;      // gating: thread owns (batch bb, unit ub)
  const int col = 16 * w + ub;
  float creg = (t0 == 0) ? 0.f : CST[bb * 1024 + col];

  // A-frag: k = ks*256 + kk*16 + lhi*8 + j -> kc = ks*32 + 2kk + lhi; b = mh*32+l31
  const int afrag_elem = ((ks * 32 + lhi) * 64 + mh * 32 + l31) * 8;
  const int lrD = nh * 32 + l31;               // C/D column -> local gate-row

  for (int tl = 0; tl < 64; ++tl) {
    const int lt = t0 + tl;          // layer-local step (0 -> h_prev = 0)
    const int gt = gb0 + tl;         // global step (ring slot & flag value)

    *(f32x4*)&R[tid * 4] = f32x4{0.f, 0.f, 0.f, 0.f};
    const u16* Gr = G + ((size_t)tl * 64 + bb) * 4096 + col;
    float g0 = bf2f(Gr[0]), g1 = bf2f(Gr[1024]), g2 = bf2f(Gr[2048]), g3 = bf2f(Gr[3072]);

    f32x16 acc = {};
    const bool doGemm = (lt > 0);
    if (doGemm) {
      const u16* Ab = HRING + (size_t)((gt - 1) & 63) * 65536 + afrag_elem;
      uint4 af[4];
#pragma unroll
      for (int p = 0; p < 4; ++p) af[p] = *(const uint4*)(Ab + p * 1024);
#pragma unroll
      for (int kk = 0; kk < 16; ++kk) {
        uint4 cur = af[kk & 3];
        if (kk + 4 < 16) af[kk & 3] = *(const uint4*)(Ab + (size_t)(kk + 4) * 1024);
        acc = __builtin_amdgcn_mfma_f32_32x32x16_bf16(
            __builtin_bit_cast(bf16x8, cur), wf[kk], acc, 0, 0, 0);
      }
    }
    __syncthreads();                 // R zeros visible
    if (doGemm) {
#pragma unroll
      for (int r = 0; r < 16; ++r) {
        int m = (r & 3) + 8 * (r >> 2) + 4 * lhi;    // 32x32 C/D row map (m101)
        atomicAdd(&R[(mh * 32 + m) * 64 + lrD], acc[r]);
      }
    }
    __syncthreads();                 // k-partial reduction done
    {
      float pi = R[bb * 64 + ub] + g0;
      float pf = R[bb * 64 + 16 + ub] + g1;
      float pg = R[bb * 64 + 32 + ub] + g2;
      float po = R[bb * 64 + 48 + ub] + g3;
      float iv = sigf(pi), fv = sigf(pf), gv = tanhf_(pg), ov = sigf(po);
      creg = fv * creg + iv * gv;
      float hv = ov * tanhf_(creg);
      u16 hb = f2bf(hv);
      unsigned hi = (unsigned)(u16)__shfl_down((int)(unsigned)hb, 1, 64);
      unsigned packed = (unsigned)hb | (hi << 16);
      if ((ub & 1) == 0) {
        size_t elem = ((size_t)(col >> 3) * 64 + bb) * 8 + (col & 7);
        unsigned* p = (unsigned*)(HRING + (size_t)(gt & 63) * 65536 + elem);
        __hip_atomic_store(p, packed, __ATOMIC_RELAXED, __HIP_MEMORY_SCOPE_SYSTEM);
        *(unsigned*)(Hout + ((size_t)lt * 64 + bb) * 1024 + col) = packed;
      }
    }
    __syncthreads();   // every wave drains vmcnt(0) before s_barrier -> h stores at LLC
    // ---- distributed flag barrier ----
    if (tid == 0)
      __hip_atomic_store(&FLAG[w * 32], (unsigned)(gt + 1),
                         __ATOMIC_RELAXED, __HIP_MEMORY_SCOPE_SYSTEM);
    if (wv == 0) {
      const unsigned tgt = (unsigned)(gt + 1);
      for (;;) {
        unsigned f = __hip_atomic_load(&FLAG[lane * 32],
                                       __ATOMIC_RELAXED, __HIP_MEMORY_SCOPE_SYSTEM);
        if (__ballot(f >= tgt) == ~0ull) break;
        __builtin_amdgcn_s_sleep(1);
      }
    }
    __syncthreads();
  }
  CST[bb * 1024 + col] = creg;
}

// ---------------- head ----------------
__global__ void lstm_head(const u16* __restrict__ Hl, const float* __restrict__ fcw,
                          const float* __restrict__ fcb, float* __restrict__ out) {
  int t = blockIdx.x, tid = threadIdx.x;
  const u16* hrow = Hl + ((size_t)t * 64 + 63) * 1024;   // batch index 63
  float s = 0.f;
  for (int j = tid; j < 1024; j += 256)
    s += sigf(bf2f(hrow[j])) * fcw[j];
  for (int o = 32; o; o >>= 1) s += __shfl_down(s, o, 64);
  __shared__ float red[4];
  if ((tid & 63) == 0) red[tid >> 6] = s;
  __syncthreads();
  if (tid == 0) out[t] = red[0] + red[1] + red[2] + red[3] + fcb[0];
}

// ---------------- launch ----------------
extern "C" void kernel_launch(void* const* d_in, const int* in_sizes, int n_in,
                              void* d_out, int out_size, void* d_ws, size_t ws_size,
                              hipStream_t stream) {
  const float* x    = (const float*)d_in[0];
  const float* wih0 = (const float*)d_in[1];
  const float* wihr = (const float*)d_in[2];
  const float* whh  = (const float*)d_in[3];
  const float* bih  = (const float*)d_in[4];
  const float* bhh  = (const float*)d_in[5];
  const float* fcw  = (const float*)d_in[6];
  const float* fcb  = (const float*)d_in[7];
  float* out = (float*)d_out;

  char* ws = (char*)d_ws;
  size_t off = 0;
  auto alc = [&](size_t b) { void* p = ws + off; off = (off + b + 255) & ~(size_t)255; return p; };
  u16* WIH   = (u16*)alc(4ull * 4096 * 1024 * 2);
  u16* WHH   = (u16*)alc(4ull * 4096 * 1024 * 2);
  float* BIAS = (float*)alc(4 * 4096 * 4);
  u16* XBUF  = (u16*)alc(32768ull * 1024 * 2);
  u16* HBUF  = (u16*)alc(32768ull * 1024 * 2);
  u16* GBUF  = (u16*)alc(64ull * 64 * 4096 * 2);
  u16* HRING = (u16*)alc(64ull * 65536 * 2);    // 8 MB h ring
  float* CST = (float*)alc(64 * 1024 * 4);
  unsigned* FLAG = (unsigned*)alc(64 * 32 * 4); // one 128B line per WG
  (void)ws_size; (void)in_sizes; (void)n_in; (void)out_size;

  hipMemsetAsync(FLAG, 0, 64 * 32 * 4, stream);
  cvt4<<<dim3(4194304 / 256), 256, 0, stream>>>((const float4*)x,    XBUF, 4194304);
  cvt4<<<dim3(524288 / 256),  256, 0, stream>>>((const float4*)wih0, WIH, 524288);
  cvt4<<<dim3(3145728 / 256), 256, 0, stream>>>((const float4*)wihr, WIH + 4194304, 3145728);
  cvt4<<<dim3(4194304 / 256), 256, 0, stream>>>((const float4*)whh,  WHH, 4194304);
  bias_add<<<dim3(64), 256, 0, stream>>>(bih, bhh, BIAS);

  for (int l = 0; l < 4; ++l) {
    const u16* Xin = (l & 1) ? HBUF : XBUF;
    u16* Ho        = (l & 1) ? XBUF : HBUF;
    const int Kd = (l == 0) ? 512 : 1024;
    const u16* Wih   = WIH + (size_t)l * 4194304;
    const u16* Whh_l = WHH + (size_t)l * 4194304;
    for (int t0 = 0; t0 < 512; t0 += 64) {
      gemm_gx<<<dim3(32, 32), 256, 0, stream>>>(Xin + (size_t)t0 * 64 * Kd, Kd, Wih,
                                                BIAS + l * 4096, GBUF);
      lstm_recur<<<dim3(64), 1024, 0, stream>>>(GBUF, Whh_l, Ho, HRING, CST, FLAG,
                                                t0, l * 512 + t0);
    }
  }
  lstm_head<<<dim3(512), 256, 0, stream>>>(XBUF, fcw, fcb, out);
}

// Round 4
// 14784.772 us; speedup vs baseline: 4.6713x; 3.7176x over previous
//
#include <hip/hip_runtime.h>

// LSTM: T=512, B=64, IN=512, H=1024, 4H=4096, LAYERS=4, OUT=1
// R4: layer-wavefront pipelining — ONE cooperative kernel, 256 WGs (4 layers x
// 64), 515 global steps (vs 2048). Input GEMM folded into the recurrence:
// gates_l(t) = Wcat_l @ [h_{l-1}(t); h_l(t-1)] + b   (layer0: [x(t); h_0(t-1)])
// W register-stationary (128 VGPR/wave), 32x32x16 MFMA, 2 m-tiles/wave.
// h exchanged via depth-32 ring, agent-scope write-through stores, plain cached
// reads (slots L2-evicted long before reuse). Hierarchical flag/epoch barrier.

typedef unsigned short u16;
typedef short bf16x8 __attribute__((ext_vector_type(8)));
typedef float f32x4 __attribute__((ext_vector_type(4)));
typedef float f32x16 __attribute__((ext_vector_type(16)));

__device__ __forceinline__ u16 f2bf(float f) {
  unsigned u = __float_as_uint(f);
  return (u16)((u + 0x7FFFu + ((u >> 16) & 1u)) >> 16);   // RNE
}
__device__ __forceinline__ float bf2f(u16 s) {
  return __uint_as_float(((unsigned)s) << 16);
}
__device__ __forceinline__ bf16x8 ld8(const u16* p) {
  uint4 v = *(const uint4*)p;
  return __builtin_bit_cast(bf16x8, v);
}
__device__ __forceinline__ float sigf(float x) {
  x = fminf(fmaxf(x, -30.f), 30.f);
  return 1.f / (1.f + __expf(-x));
}
__device__ __forceinline__ float tanhf_(float x) {
  x = fminf(fmaxf(x, -15.f), 15.f);
  float e = __expf(-2.f * x);
  return (1.f - e) / (1.f + e);
}

#define AT_LD(p) __hip_atomic_load((p), __ATOMIC_RELAXED, __HIP_MEMORY_SCOPE_AGENT)
#define AT_ST(p, v) __hip_atomic_store((p), (v), __ATOMIC_RELAXED, __HIP_MEMORY_SCOPE_AGENT)

// ---------------- repack: W -> WCAT[l][4096][2048] bf16 ----------------
// cols [0,Kx) = W_ih_l, [Kx,Kx+1024) = W_hh_l, rest 0. Kx = 512 (l=0) else 1024.
__global__ void repack_w(const float* __restrict__ wih0, const float* __restrict__ wihr,
                         const float* __restrict__ whh, u16* __restrict__ WCAT) {
  size_t i = (size_t)blockIdx.x * 256 + threadIdx.x;   // 33554432 total
  int l = (int)(i >> 23);
  int r = (int)(i >> 11) & 4095;
  int c = (int)i & 2047;
  int Kx = l ? 1024 : 512;
  float v = 0.f;
  if (c < Kx) v = l ? wihr[((size_t)(l - 1) * 4096 + r) * 1024 + c]
                    : wih0[(size_t)r * 512 + c];
  else if (c < Kx + 1024) v = whh[((size_t)l * 4096 + r) * 1024 + (c - Kx)];
  WCAT[i] = f2bf(v);
}

// ---------------- repack: x -> XP[t][kc(64)][b(64)][8] bf16 ----------------
__global__ void repack_x(const float* __restrict__ x, u16* __restrict__ XP) {
  int i = blockIdx.x * 256 + threadIdx.x;   // 2097152 total
  int t = i >> 12, r = i & 4095, kc = r >> 6, b = r & 63;
  const float* src = x + ((size_t)t * 64 + b) * 512 + kc * 8;
  float4 v0 = *(const float4*)src, v1 = *(const float4*)(src + 4);
  u16 o[8] = {f2bf(v0.x), f2bf(v0.y), f2bf(v0.z), f2bf(v0.w),
              f2bf(v1.x), f2bf(v1.y), f2bf(v1.z), f2bf(v1.w)};
  *(uint4*)(XP + ((size_t)(t * 64 + kc) * 64 + b) * 8) = *(uint4*)o;
}

__global__ void bias_add(const float* __restrict__ a, const float* __restrict__ b,
                         float* __restrict__ o) {
  int i = blockIdx.x * blockDim.x + threadIdx.x;   // 16384 total
  o[i] = a[i] + b[i];
}

// ---------------- pipelined recurrence ----------------
// WG w: layer = w>>6, owns units [16(w&63), +16) -> 64 gate-rows.
// 8 waves = (ks in 0..3, nh in 0..1): K-slice of NF frags (16k each), rows 32nh..+32.
// Each wave: 2 m-tiles (batch 0..31, 32..63) -> acc0/acc1, shared wf[] B-frags.
template <int NF, int FX>
__device__ __forceinline__ void run_pipe(
    int layer, int w64, const u16* __restrict__ WCAT, const u16* __restrict__ XP,
    u16* __restrict__ HR, u16* __restrict__ HOUT, const float* __restrict__ BIAS,
    unsigned* __restrict__ FLAG, unsigned* __restrict__ EPOCH, float* R) {
  const int tid = threadIdx.x;
  const int lane = tid & 63, wv = tid >> 6;
  const int ks = wv & 3, nh = wv >> 2;
  const int l31 = lane & 31, lhi = lane >> 5;
  const int W = layer * 64 + w64;

  // ---- W preload: NF frags = 4*NF VGPRs, persistent ----
  bf16x8 wf[NF];
  {
    const int lr = nh * 32 + l31;
    const int grow = (lr >> 4) * 1024 + 16 * w64 + (lr & 15);
    const u16* wrow = WCAT + ((size_t)layer * 4096 + grow) * 2048;
#pragma unroll
    for (int kk = 0; kk < NF; ++kk) {
      int f = ks * NF + kk;
      wf[kk] = ld8(wrow + f * 16 + lhi * 8);
    }
  }

  const int u = tid & 15, bp = tid >> 4;       // gating: (batch bp & bp+32, unit u)
  const int col = 16 * w64 + u;
  float c0 = 0.f, c1 = 0.f;
  const float bi = BIAS[layer * 4096 + col];
  const float bf_ = BIAS[layer * 4096 + 1024 + col];
  const float bg = BIAS[layer * 4096 + 2048 + col];
  const float bo = BIAS[layer * 4096 + 3072 + col];

  const int lane_base = (lhi * 64 + l31) * 8;  // mt0; mt1 adds +256 elems
  u16* HRL = HR + (size_t)layer * 2097152;                       // own ring (32 slots)
  const u16* M0B = (NF == 32) ? HR + (size_t)(layer - 1) * 2097152 : XP;
  const int lrD = nh * 32 + l31;               // C/D col -> local gate-row

  for (int s = 0; s < 515; ++s) {
    const int t = s - layer;
    const bool active = (t >= 0) && (t < 512);   // WG-uniform
    if (active) {
      *(f32x4*)&R[tid * 8] = f32x4{0.f, 0.f, 0.f, 0.f};
      *(f32x4*)&R[tid * 8 + 4] = f32x4{0.f, 0.f, 0.f, 0.f};
      __syncthreads();

      const u16* P0 = M0B + ((NF == 32) ? (size_t)(t & 31) * 65536
                                        : (size_t)t * 32768) + lane_base;
      const u16* P1 = HRL + (size_t)((t - 1) & 31) * 65536 + lane_base - (size_t)FX * 1024;

      f32x16 acc0 = {}, acc1 = {};
      uint4 a0[4], a1[4];
#pragma unroll
      for (int p = 0; p < 4; ++p) {
        int f = ks * NF + p;
        const u16* ap = (f < FX ? P0 : P1) + (size_t)f * 1024;
        a0[p] = *(const uint4*)ap;
        a1[p] = *(const uint4*)(ap + 256);
      }
#pragma unroll
      for (int kk = 0; kk < NF; ++kk) {
        uint4 ca = a0[kk & 3], cb = a1[kk & 3];
        if (kk + 4 < NF) {
          int f = ks * NF + kk + 4;
          const u16* ap = (f < FX ? P0 : P1) + (size_t)f * 1024;
          a0[kk & 3] = *(const uint4*)ap;
          a1[kk & 3] = *(const uint4*)(ap + 256);
        }
        acc0 = __builtin_amdgcn_mfma_f32_32x32x16_bf16(
            __builtin_bit_cast(bf16x8, ca), wf[kk], acc0, 0, 0, 0);
        acc1 = __builtin_amdgcn_mfma_f32_32x32x16_bf16(
            __builtin_bit_cast(bf16x8, cb), wf[kk], acc1, 0, 0, 0);
      }
#pragma unroll
      for (int r = 0; r < 16; ++r) {
        int m = (r & 3) + 8 * (r >> 2) + 4 * lhi;    // 32x32 C/D row map (m101)
        atomicAdd(&R[m * 64 + lrD], acc0[r]);
        atomicAdd(&R[(32 + m) * 64 + lrD], acc1[r]);
      }
      __syncthreads();
      {
        float p0i = R[bp * 64 + u] + bi, p0f = R[bp * 64 + 16 + u] + bf_;
        float p0g = R[bp * 64 + 32 + u] + bg, p0o = R[bp * 64 + 48 + u] + bo;
        float p1i = R[(bp + 32) * 64 + u] + bi, p1f = R[(bp + 32) * 64 + 16 + u] + bf_;
        float p1g = R[(bp + 32) * 64 + 32 + u] + bg, p1o = R[(bp + 32) * 64 + 48 + u] + bo;
        c0 = sigf(p0f) * c0 + sigf(p0i) * tanhf_(p0g);
        float h0 = sigf(p0o) * tanhf_(c0);
        c1 = sigf(p1f) * c1 + sigf(p1i) * tanhf_(p1g);
        float h1 = sigf(p1o) * tanhf_(c1);
        u16 hb0 = f2bf(h0), hb1 = f2bf(h1);
        unsigned n0 = (unsigned)(u16)__shfl_down((int)(unsigned)hb0, 1, 64);
        unsigned n1 = (unsigned)(u16)__shfl_down((int)(unsigned)hb1, 1, 64);
        if ((u & 1) == 0) {
          unsigned pk0 = (unsigned)hb0 | (n0 << 16);
          unsigned pk1 = (unsigned)hb1 | (n1 << 16);
          u16* slot = HRL + (size_t)(t & 31) * 65536;
          size_t e0 = ((size_t)(col >> 3) * 64 + bp) * 8 + (col & 7);
          AT_ST((unsigned*)(slot + e0), pk0);
          AT_ST((unsigned*)(slot + e0 + 256), pk1);   // b+32
          if (layer == 3 && bp == 31)                 // batch 63 for the head
            *(unsigned*)(HOUT + (size_t)t * 1024 + col) = pk1;
        }
      }
      __syncthreads();   // drains vmcnt(0): ring stores at coherence point
    }
    // ---- hierarchical barrier ----
    const unsigned tgt = (unsigned)(s + 1);
    if (tid == 0) AT_ST(&FLAG[W * 64], tgt);
    if (W == 0) {
      if (wv == 0) {
        for (;;) {
          unsigned f0 = AT_LD(&FLAG[lane * 64]);
          unsigned f1 = AT_LD(&FLAG[(lane + 64) * 64]);
          unsigned f2 = AT_LD(&FLAG[(lane + 128) * 64]);
          unsigned f3 = AT_LD(&FLAG[(lane + 192) * 64]);
          bool ok = (f0 >= tgt) & (f1 >= tgt) & (f2 >= tgt) & (f3 >= tgt);
          if (__ballot(ok) == ~0ull) break;
          __builtin_amdgcn_s_sleep(1);
        }
        if (lane < 32) AT_ST(&EPOCH[lane * 64], tgt);   // 32 replicas
      }
    } else if (wv == 0) {
      unsigned* ep = &EPOCH[(W & 31) * 64];
      while (AT_LD(ep) < tgt) __builtin_amdgcn_s_sleep(1);
    }
    __syncthreads();
  }
}

__global__ __launch_bounds__(512, 2) void lstm_pipe(
    const u16* __restrict__ WCAT, const u16* __restrict__ XP,
    u16* __restrict__ HR, u16* __restrict__ HOUT,
    const float* __restrict__ BIAS, unsigned* __restrict__ FLAG,
    unsigned* __restrict__ EPOCH) {
  __shared__ float R[64 * 64];
  const int w = blockIdx.x;
  const int layer = w >> 6, w64 = w & 63;
  if (layer == 0) run_pipe<24, 32>(0, w64, WCAT, XP, HR, HOUT, BIAS, FLAG, EPOCH, R);
  else            run_pipe<32, 64>(layer, w64, WCAT, XP, HR, HOUT, BIAS, FLAG, EPOCH, R);
}

// ---------------- head: out[t] = sigmoid(h3[t][63][:]) . fcw + fcb ----------------
__global__ void lstm_head(const u16* __restrict__ Hl, const float* __restrict__ fcw,
                          const float* __restrict__ fcb, float* __restrict__ out) {
  int t = blockIdx.x, tid = threadIdx.x;
  const u16* hrow = Hl + (size_t)t * 1024;
  float s = 0.f;
  for (int j = tid; j < 1024; j += 256)
    s += sigf(bf2f(hrow[j])) * fcw[j];
  for (int o = 32; o; o >>= 1) s += __shfl_down(s, o, 64);
  __shared__ float red[4];
  if ((tid & 63) == 0) red[tid >> 6] = s;
  __syncthreads();
  if (tid == 0) out[t] = red[0] + red[1] + red[2] + red[3] + fcb[0];
}

// ---------------- launch ----------------
extern "C" void kernel_launch(void* const* d_in, const int* in_sizes, int n_in,
                              void* d_out, int out_size, void* d_ws, size_t ws_size,
                              hipStream_t stream) {
  const float* x    = (const float*)d_in[0];
  const float* wih0 = (const float*)d_in[1];
  const float* wihr = (const float*)d_in[2];
  const float* whh  = (const float*)d_in[3];
  const float* bih  = (const float*)d_in[4];
  const float* bhh  = (const float*)d_in[5];
  const float* fcw  = (const float*)d_in[6];
  const float* fcb  = (const float*)d_in[7];
  float* out = (float*)d_out;

  char* ws = (char*)d_ws;
  size_t off = 0;
  auto alc = [&](size_t b) { void* p = ws + off; off = (off + b + 255) & ~(size_t)255; return p; };
  u16* WCAT  = (u16*)alc(33554432ull * 2);   // 64 MB
  u16* XP    = (u16*)alc(16777216ull * 2);   // 32 MB
  u16* HR    = (u16*)alc(8388608ull * 2);    // 16 MB (4 layers x 32 slots x 128 KB)
  u16* HOUT  = (u16*)alc(524288ull * 2);     // 1 MB
  float* BIAS = (float*)alc(16384 * 4);
  unsigned* FLAG  = (unsigned*)alc(256 * 64 * 4);
  unsigned* EPOCH = (unsigned*)alc(32 * 64 * 4);
  (void)ws_size; (void)in_sizes; (void)n_in; (void)out_size;

  hipMemsetAsync(HR, 0, 8388608ull * 2, stream);
  hipMemsetAsync(FLAG, 0, 256 * 64 * 4, stream);
  hipMemsetAsync(EPOCH, 0, 32 * 64 * 4, stream);
  repack_w<<<dim3(131072), 256, 0, stream>>>(wih0, wihr, whh, WCAT);
  repack_x<<<dim3(8192), 256, 0, stream>>>(x, XP);
  bias_add<<<dim3(64), 256, 0, stream>>>(bih, bhh, BIAS);

  void* args[] = {&WCAT, &XP, &HR, &HOUT, &BIAS, &FLAG, &EPOCH};
  hipLaunchCooperativeKernel((const void*)lstm_pipe, dim3(256), dim3(512),
                             args, 0, stream);

  lstm_head<<<dim3(512), 256, 0, stream>>>(HOUT, fcw, fcb, out);
}